// Round 6
// baseline (474.876 us; speedup 1.0000x reference)
//
#include <hip/hip_runtime.h>

// out[m][n] = C[m][n] * D[n];  M = NR = 8192, fp32.
// INSTRUMENTED PROBE (single kernel, single launch — multi-launch sources
// failed the harness 2/2, single-launch always runs).
//
// Every fast variant (~96-100us inferred) hides below the ~162us re-poison
// fills in the rocprof top-5, so no counters. This round: same shipping
// kernel body repeated 2x internally (~190us -> visible) to read its own
// FETCH/WRITE/dur directly and resolve BW-bound (~5.6 TB/s, roofline) vs
// latency-bound (~4.2 TB/s effective, headroom remains).
//
// asm volatile "+v"(i) between reps: compiler must assume the index changed,
// so rep-0's store cannot be dead-store-eliminated and rep-1's load cannot
// be CSE'd. Both reps compute identical values -> output still correct.

#define NR 8192
#define M_ROWS 8192
#define NC4 (NR / 4)                    // 2048 float4 per row
#define N4 ((M_ROWS * NR) / 4)          // 16,777,216 float4 total
#define THREADS 256
#define REPS 2

typedef float v4 __attribute__((ext_vector_type(4)));

__global__ __launch_bounds__(256) void colscale_x2(
    const v4* __restrict__ C4,
    const v4* __restrict__ D4,
    v4* __restrict__ O4)
{
    unsigned i = blockIdx.x * THREADS + threadIdx.x;
    const v4 d = D4[i & (NC4 - 1)];      // hoisted: loaded once
#pragma unroll 1
    for (int rep = 0; rep < REPS; ++rep) {
        v4 c = C4[i];                               // cached load
        __builtin_nontemporal_store(c * d, &O4[i]); // nt store (current best cfg)
        asm volatile("" : "+v"(i));                 // keep reps distinct
    }
}

extern "C" void kernel_launch(void* const* d_in, const int* in_sizes, int n_in,
                              void* d_out, int out_size, void* d_ws, size_t ws_size,
                              hipStream_t stream) {
    const v4* C4 = (const v4*)d_in[0];
    const v4* D4 = (const v4*)d_in[1];
    v4* O4 = (v4*)d_out;

    colscale_x2<<<N4 / THREADS, THREADS, 0, stream>>>(C4, D4, O4);
}